// Round 8
// baseline (303.228 us; speedup 1.0000x reference)
//
#include <hip/hip_runtime.h>
#include <hip/hip_bf16.h>
#include <stdint.h>

#define DIM 512
#define NROWS 1024
#define NCLS 100000
#define NST 391                         // stripes of 256 cols
#define NCLS_PAD (NST * 256)            // 100096
#define SCALE_S 64.0f
#define NBN 64                          // stripe-columns covered by the grid
#define S_LOG2E 92.332482616893662f     // 64 * log2(e)

typedef __attribute__((ext_vector_type(8))) __bf16 bf16x8;
typedef __attribute__((ext_vector_type(4))) float f32x4;

__device__ __forceinline__ unsigned short f2bf(float x) {
  __hip_bfloat16 h = __float2bfloat16(x);
  union { __hip_bfloat16 h; unsigned short u; } v; v.h = h; return v.u;
}
__device__ __forceinline__ unsigned pack2(float a, float b) {
  return ((unsigned)f2bf(b) << 16) | (unsigned)f2bf(a);
}
__device__ __forceinline__ void async_ld16(const void* g, void* l) {
  __builtin_amdgcn_global_load_lds((const __attribute__((address_space(1))) void*)g,
                                   (__attribute__((address_space(3))) void*)l, 16, 0, 0);
}

// ---------------- kernel 1a: normalize inputs -> bf16 ----------------
__global__ void prep_a(const float* __restrict__ X, unsigned short* __restrict__ A16,
                       float* __restrict__ xnorm) {
  const int row = blockIdx.x;
  const int lane = threadIdx.x;  // 64
  const float4* xp = (const float4*)(X + (size_t)row * DIM);
  float4 v0 = xp[lane];
  float4 v1 = xp[lane + 64];
  float ss = v0.x*v0.x + v0.y*v0.y + v0.z*v0.z + v0.w*v0.w
           + v1.x*v1.x + v1.y*v1.y + v1.z*v1.z + v1.w*v1.w;
  #pragma unroll
  for (int m = 1; m < 64; m <<= 1) ss += __shfl_xor(ss, m);
  const float nrm = sqrtf(ss);
  const float inv = 1.0f / fmaxf(nrm, 1e-12f);
  if (lane == 0) xnorm[row] = nrm;
  unsigned short* ap = A16 + (size_t)row * DIM;
  *(uint2*)(ap + lane * 4)       = make_uint2(pack2(v0.x*inv, v0.y*inv), pack2(v0.z*inv, v0.w*inv));
  *(uint2*)(ap + 256 + lane * 4) = make_uint2(pack2(v1.x*inv, v1.y*inv), pack2(v1.z*inv, v1.w*inv));
}

// ---------------- kernel 1b: normalize weight rows -> bf16 (padded to 100096) ----------------
__global__ void prep_w(const float* __restrict__ Wg, unsigned short* __restrict__ W16) {
  const int row = blockIdx.x * 4 + (threadIdx.x >> 6);
  const int lane = threadIdx.x & 63;
  unsigned short* op = W16 + (size_t)row * DIM;
  if (row >= NCLS) {                       // zero-pad tail rows (cos=0 -> exp(-64)~0)
    *(uint4*)((char*)op + lane * 16) = make_uint4(0, 0, 0, 0);
    return;
  }
  const float4* xp = (const float4*)(Wg + (size_t)row * DIM);
  float4 v0 = xp[lane];
  float4 v1 = xp[lane + 64];
  float ss = v0.x*v0.x + v0.y*v0.y + v0.z*v0.z + v0.w*v0.w
           + v1.x*v1.x + v1.y*v1.y + v1.z*v1.z + v1.w*v1.w;
  #pragma unroll
  for (int m = 1; m < 64; m <<= 1) ss += __shfl_xor(ss, m);
  const float inv = 1.0f / fmaxf(sqrtf(ss), 1e-12f);
  *(uint2*)(op + lane * 4)       = make_uint2(pack2(v0.x*inv, v0.y*inv), pack2(v0.z*inv, v0.w*inv));
  *(uint2*)(op + 256 + lane * 4) = make_uint2(pack2(v1.x*inv, v1.y*inv), pack2(v1.z*inv, v1.w*inv));
}

// ---------------- kernel 2: 256-tile GEMM + fixed-max sumexp partials ----------------
// 512 threads (8 waves = 2M x 4N), block tile BM=256 x stripe 256, BK=64.
// Per wave output 128x64 (Mw=128) -> 375 B LDS-read per MFMA (vs 512 before).
// A+B K-tiles double-buffered in 128KB LDS, staged via global_load_lds (w=16,
// pre-swizzled source, XOR (row&7)<<4). Two raw barriers per K-tile, counted
// s_waitcnt vmcnt(8) (never 0 mid-pipeline), continuous across stripes.
//
// Race-freedom: segment t (between barrier pairs) stages into slot (t+1)&1 and
// computes slot t&1. Compute of slot (t+1)&1 finished in segment t-1, and all
// waves passed barrier-a of segment t before any staging -> no overwrite race.

__device__ __forceinline__ void stage_tile(const char* Ab, const char* W16g,
                                           long col0, int kt, int slot,
                                           int wave, int lane, char* lds) {
  char* dstA = lds + slot * 65536;
  char* dstB = dstA + 32768;
  const char* Wb = W16g + (size_t)col0 * 1024;
  #pragma unroll
  for (int it = 0; it < 4; ++it) {
    const int chunk = wave * 4 + it;               // 32 chunks x 1KB each
    const int d = chunk * 1024 + lane * 16;        // linear LDS byte this lane fills
    const int row = d >> 7;                        // tile row/col (128B per row)
    const int b = d & 127;
    const int srel = row * 1024 + kt * 128 + (b ^ ((row & 7) << 4)); // pre-swizzled src
    async_ld16(Ab + srel, dstA + chunk * 1024);    // dest: wave-uniform base
    async_ld16(Wb + srel, dstB + chunk * 1024);
  }
}

__device__ __forceinline__ void compute_tile(const char* lds, int slot, int wr, int wn,
                                             int lr, int lg, f32x4 (&acc)[8][4]) {
  const char* Ab = lds + slot * 65536;
  const char* Bb = Ab + 32768;
  #pragma unroll
  for (int kh = 0; kh < 2; ++kh) {
    bf16x8 afr[8]; bf16x8 bfr[4];
    #pragma unroll
    for (int mi = 0; mi < 8; ++mi) {
      const int row = wr * 128 + mi * 16 + lr;
      afr[mi] = *(const bf16x8*)(Ab + row * 128 + ((kh * 64 + lg * 16) ^ ((row & 7) << 4)));
    }
    #pragma unroll
    for (int ni = 0; ni < 4; ++ni) {
      const int col = wn * 64 + ni * 16 + lr;
      bfr[ni] = *(const bf16x8*)(Bb + col * 128 + ((kh * 64 + lg * 16) ^ ((col & 7) << 4)));
    }
    #pragma unroll
    for (int mi = 0; mi < 8; ++mi)
      #pragma unroll
      for (int ni = 0; ni < 4; ++ni)
        acc[mi][ni] = __builtin_amdgcn_mfma_f32_16x16x32_bf16(afr[mi], bfr[ni], acc[mi][ni], 0, 0, 0);
  }
}

__global__ __launch_bounds__(512, 2) void gemm_lse3(
    const unsigned short* __restrict__ A16, const unsigned short* __restrict__ W16,
    float* __restrict__ part_s) {
  __shared__ char lds[2 * 65536];          // 128 KB: 2 x (A 32KB + B 32KB)
  const char* W16g = (const char*)W16;

  const int tid = threadIdx.x;
  const int lane = tid & 63;
  const int wave = tid >> 6;               // 0..7
  const int lr = lane & 15, lg = lane >> 4;
  const int wr = wave >> 2;                // M half: 0..1
  const int wn = wave & 3;                 // N quarter: 0..3

  // bid -> (mblk, nblk): 4 mblks of one stripe-column land on one XCD (bid&7)
  const int bid = blockIdx.x;              // 256 blocks
  const int x = bid & 7;
  const int q = bid >> 3;                  // 0..31
  const int mblk = q & 3;                  // 0..3
  const int nblk = x * 8 + (q >> 2);       // 0..63
  const int mrow0 = mblk * 256;

  const char* Ab = (const char*)A16 + (size_t)mrow0 * 1024;

  f32x4 acc[8][4];
  #pragma unroll
  for (int mi = 0; mi < 8; ++mi)
    #pragma unroll
    for (int ni = 0; ni < 4; ++ni) acc[mi][ni] = f32x4{0.f, 0.f, 0.f, 0.f};
  float srow[8][4];
  #pragma unroll
  for (int mi = 0; mi < 8; ++mi)
    #pragma unroll
    for (int r = 0; r < 4; ++r) srow[mi][r] = 0.f;

  long s = nblk;                           // stripe index
  long col0 = s * 256;
  stage_tile(Ab, W16g, col0, 0, 0, wave, lane, lds);   // prologue: tile 0 -> slot 0

  while (true) {
    const bool more = (s + NBN) < NST;
    const long ncol0 = (s + NBN) * 256;

    #pragma unroll
    for (int t = 0; t < 8; ++t) {
      __builtin_amdgcn_s_barrier();        // a: compute of slot (t+1)&1 done everywhere
      if (t < 7)      stage_tile(Ab, W16g, col0, t + 1, (t + 1) & 1, wave, lane, lds);
      else if (more)  stage_tile(Ab, W16g, ncol0, 0, 0, wave, lane, lds);
      if (t == 7 && !more) { asm volatile("s_waitcnt vmcnt(0)" ::: "memory"); }
      else                 { asm volatile("s_waitcnt vmcnt(8)" ::: "memory"); }
      __builtin_amdgcn_s_barrier();        // b: tile t (slot t&1) staged & visible
      compute_tile(lds, t & 1, wr, wn, lr, lg, acc);
    }

    // ---- register-only epilogue: fixed max = S, srow += exp2(fma(c,K,-K)) ----
    // (zero-padded W cols contribute exp2(-92.3) ~ 2e-28 -> no masking needed)
    #pragma unroll
    for (int mi = 0; mi < 8; ++mi)
      #pragma unroll
      for (int ni = 0; ni < 4; ++ni)
        #pragma unroll
        for (int r = 0; r < 4; ++r) {
          float c = fminf(1.f, fmaxf(-1.f, acc[mi][ni][r]));   // med3
          srow[mi][r] += exp2f(fmaf(c, S_LOG2E, -S_LOG2E));
          acc[mi][ni][r] = 0.f;
        }

    if (!more) break;
    s += NBN; col0 = ncol0;
  }

  // ---- reduce: lr-lanes (16 cols) in-wave, then 4 wn-waves via LDS ----
  float* ldsrow = (float*)lds;             // 4 wn x 256 rows (pipeline done, LDS free)
  __builtin_amdgcn_s_barrier();
  #pragma unroll
  for (int mi = 0; mi < 8; ++mi)
    #pragma unroll
    for (int r = 0; r < 4; ++r) {
      float v = srow[mi][r];
      v += __shfl_xor(v, 1); v += __shfl_xor(v, 2);
      v += __shfl_xor(v, 4); v += __shfl_xor(v, 8);
      if (lr == 0)
        ldsrow[wn * 256 + wr * 128 + mi * 16 + lg * 4 + r] = v;
    }
  __builtin_amdgcn_s_barrier();
  asm volatile("s_waitcnt lgkmcnt(0)" ::: "memory");
  if (tid < 256) {
    float v = ldsrow[tid] + ldsrow[256 + tid] + ldsrow[512 + tid] + ldsrow[768 + tid];
    part_s[(size_t)nblk * NROWS + mrow0 + tid] = v;
  }
}

// ---------------- kernel 3: precise f32 target logit + merge partials ----------------
__global__ void finalize_kernel(const float* __restrict__ X, const int* __restrict__ labels,
                                const float* __restrict__ Wg, const float* __restrict__ xnorm,
                                const float* __restrict__ part_s, float* __restrict__ rowloss) {
  const int row = blockIdx.x;
  const int lane = threadIdx.x;   // 64
  const int lbl = labels[row];
  const float4* xp = (const float4*)(X + (size_t)row * DIM);
  const float4* wp = (const float4*)(Wg + (size_t)lbl * DIM);
  float dot = 0.f, wss = 0.f;
  #pragma unroll
  for (int i = 0; i < 2; ++i) {
    float4 xv = xp[lane + 64 * i];
    float4 wv = wp[lane + 64 * i];
    dot += xv.x*wv.x + xv.y*wv.y + xv.z*wv.z + xv.w*wv.w;
    wss += wv.x*wv.x + wv.y*wv.y + wv.z*wv.z + wv.w*wv.w;
  }
  float psum = part_s[(size_t)lane * NROWS + row];   // 64 partials per row
  #pragma unroll
  for (int m = 1; m < 64; m <<= 1) {
    dot += __shfl_xor(dot, m); wss += __shfl_xor(wss, m); psum += __shfl_xor(psum, m);
  }
  if (lane == 0) {
    float c = dot / (fmaxf(xnorm[row], 1e-12f) * fmaxf(sqrtf(wss), 1e-12f));
    c = fminf(1.f, fmaxf(-1.f, c));
    const float cm = 0.99500416527802576610f;   // cos(0.1)
    const float sn = 0.09983341664682815230f;   // sin(0.1)
    float unmod = SCALE_S * c;                  // term the GEMM summed at the label column
    float modv  = SCALE_S * (c * cm - sqrtf(fmaxf(0.f, 1.f - c * c)) * sn); // S*cos(theta+m)
    float stot = psum - __expf(unmod - SCALE_S) + __expf(modv - SCALE_S);
    stot = fmaxf(stot, 1e-37f);
    rowloss[row] = (logf(stot) + SCALE_S) - modv;   // logsumexp - target logit
  }
}

// ---------------- kernel 4: mean over rows ----------------
__global__ void reduce_kernel(const float* __restrict__ rowloss, float* __restrict__ out) {
  const int tid = threadIdx.x;   // 256
  float s = 0.f;
  #pragma unroll
  for (int i = 0; i < 4; ++i) s += rowloss[tid + i * 256];
  #pragma unroll
  for (int m = 1; m < 64; m <<= 1) s += __shfl_xor(s, m);
  __shared__ float wsum[4];
  if ((tid & 63) == 0) wsum[tid >> 6] = s;
  __syncthreads();
  if (tid == 0) out[0] = (wsum[0] + wsum[1] + wsum[2] + wsum[3]) * (1.0f / NROWS);
}

extern "C" void kernel_launch(void* const* d_in, const int* in_sizes, int n_in,
                              void* d_out, int out_size, void* d_ws, size_t ws_size,
                              hipStream_t stream) {
  const float* X      = (const float*)d_in[0];
  const int*   labels = (const int*)d_in[1];
  const float* Wg     = (const float*)d_in[2];
  float* out = (float*)d_out;
  char* ws = (char*)d_ws;
  // ws layout (bytes):
  //   A16    @ 0            1,048,576
  //   W16    @ 1,048,576  102,498,304   (100096 x 512 x 2B, rows >= NCLS zeroed)
  //   part_s @ 103,546,880    262,144   (64 x 1024 x 4B)
  //   xnorm  @ 103,809,024      4,096
  //   rowloss@ 103,813,120      4,096
  unsigned short* A16 = (unsigned short*)ws;
  unsigned short* W16 = (unsigned short*)(ws + 1048576);
  float* part_s  = (float*)(ws + 103546880);
  float* xnorm   = (float*)(ws + 103809024);
  float* rowloss = (float*)(ws + 103813120);

  prep_a<<<NROWS, 64, 0, stream>>>(X, A16, xnorm);
  prep_w<<<NCLS_PAD / 4, 256, 0, stream>>>(Wg, W16);
  gemm_lse3<<<256, 512, 0, stream>>>(A16, W16, part_s);
  finalize_kernel<<<NROWS, 64, 0, stream>>>(X, labels, Wg, xnorm, part_s, rowloss);
  reduce_kernel<<<1, 256, 0, stream>>>(rowloss, out);
}

// Round 9
// 303.118 us; speedup vs baseline: 1.0004x; 1.0004x over previous
//
#include <hip/hip_runtime.h>
#include <hip/hip_bf16.h>
#include <stdint.h>

#define DIM 512
#define NROWS 1024
#define NCLS 100000
#define NST 391                         // stripes of 256 cols
#define NCLS_PAD (NST * 256)            // 100096
#define SCALE_S 64.0f
#define NBN 64                          // stripe-columns covered by the grid
#define S_LOG2E 92.332482616893662f     // 64 * log2(e)

typedef __attribute__((ext_vector_type(8))) __bf16 bf16x8;
typedef __attribute__((ext_vector_type(4))) float f32x4;

__device__ __forceinline__ unsigned short f2bf(float x) {
  __hip_bfloat16 h = __float2bfloat16(x);
  union { __hip_bfloat16 h; unsigned short u; } v; v.h = h; return v.u;
}
__device__ __forceinline__ unsigned pack2(float a, float b) {
  return ((unsigned)f2bf(b) << 16) | (unsigned)f2bf(a);
}
__device__ __forceinline__ void async_ld16(const void* g, void* l) {
  __builtin_amdgcn_global_load_lds((const __attribute__((address_space(1))) void*)g,
                                   (__attribute__((address_space(3))) void*)l, 16, 0, 0);
}

// ---------------- kernel 1a: normalize inputs -> bf16 ----------------
__global__ void prep_a(const float* __restrict__ X, unsigned short* __restrict__ A16,
                       float* __restrict__ xnorm) {
  const int row = blockIdx.x;
  const int lane = threadIdx.x;  // 64
  const float4* xp = (const float4*)(X + (size_t)row * DIM);
  float4 v0 = xp[lane];
  float4 v1 = xp[lane + 64];
  float ss = v0.x*v0.x + v0.y*v0.y + v0.z*v0.z + v0.w*v0.w
           + v1.x*v1.x + v1.y*v1.y + v1.z*v1.z + v1.w*v1.w;
  #pragma unroll
  for (int m = 1; m < 64; m <<= 1) ss += __shfl_xor(ss, m);
  const float nrm = sqrtf(ss);
  const float inv = 1.0f / fmaxf(nrm, 1e-12f);
  if (lane == 0) xnorm[row] = nrm;
  unsigned short* ap = A16 + (size_t)row * DIM;
  *(uint2*)(ap + lane * 4)       = make_uint2(pack2(v0.x*inv, v0.y*inv), pack2(v0.z*inv, v0.w*inv));
  *(uint2*)(ap + 256 + lane * 4) = make_uint2(pack2(v1.x*inv, v1.y*inv), pack2(v1.z*inv, v1.w*inv));
}

// ---------------- kernel 1b: normalize weight rows -> bf16 (padded to 100096) ----------------
__global__ void prep_w(const float* __restrict__ Wg, unsigned short* __restrict__ W16) {
  const int row = blockIdx.x * 4 + (threadIdx.x >> 6);
  const int lane = threadIdx.x & 63;
  unsigned short* op = W16 + (size_t)row * DIM;
  if (row >= NCLS) {                       // zero-pad tail rows (cos=0 -> exp(-64)~0)
    *(uint4*)((char*)op + lane * 16) = make_uint4(0, 0, 0, 0);
    return;
  }
  const float4* xp = (const float4*)(Wg + (size_t)row * DIM);
  float4 v0 = xp[lane];
  float4 v1 = xp[lane + 64];
  float ss = v0.x*v0.x + v0.y*v0.y + v0.z*v0.z + v0.w*v0.w
           + v1.x*v1.x + v1.y*v1.y + v1.z*v1.z + v1.w*v1.w;
  #pragma unroll
  for (int m = 1; m < 64; m <<= 1) ss += __shfl_xor(ss, m);
  const float inv = 1.0f / fmaxf(sqrtf(ss), 1e-12f);
  *(uint2*)(op + lane * 4)       = make_uint2(pack2(v0.x*inv, v0.y*inv), pack2(v0.z*inv, v0.w*inv));
  *(uint2*)(op + 256 + lane * 4) = make_uint2(pack2(v1.x*inv, v1.y*inv), pack2(v1.z*inv, v1.w*inv));
}

// ---------------- kernel 2: 256-tile GEMM + fixed-max sumexp partials ----------------
// 512 threads (8 waves = 2M x 4N), block tile BM=256 x stripe 256, BK=64.
// __launch_bounds__(512, 1): 128KB LDS means 1 block/CU regardless; round-8's
// (512,2) capped VGPR at 128 and spilled the 128-reg accumulator to scratch
// (WRITE_SIZE 82MB, MfmaUtil 16%). With a 256-reg budget: acc 128 + srow 32
// + operands ~48 + addr ~25 = ~233, no spill.
//
// A+B K-tiles double-buffered in 128KB LDS, staged via global_load_lds (w=16,
// pre-swizzled source, XOR (row&7)<<4). Two raw barriers per K-tile, counted
// s_waitcnt vmcnt(8) (never 0 mid-pipeline), continuous across stripes.
//
// Race-freedom: segment t (between barrier pairs) stages into slot (t+1)&1 and
// computes slot t&1. A wave's ds_reads of slot t&1 complete (lgkm-waited by its
// own MFMA consumption) before it reaches barrier-a of segment t+1, so staging
// into slot t&1 in segment t+1 cannot race the reads.

__device__ __forceinline__ void stage_tile(const char* Ab, const char* W16g,
                                           long col0, int kt, int slot,
                                           int wave, int lane, char* lds) {
  char* dstA = lds + slot * 65536;
  char* dstB = dstA + 32768;
  const char* Wb = W16g + (size_t)col0 * 1024;
  #pragma unroll
  for (int it = 0; it < 4; ++it) {
    const int chunk = wave * 4 + it;               // 32 chunks x 1KB each
    const int d = chunk * 1024 + lane * 16;        // linear LDS byte this lane fills
    const int row = d >> 7;                        // tile row/col (128B per row)
    const int b = d & 127;
    const int srel = row * 1024 + kt * 128 + (b ^ ((row & 7) << 4)); // pre-swizzled src
    async_ld16(Ab + srel, dstA + chunk * 1024);    // dest: wave-uniform base
    async_ld16(Wb + srel, dstB + chunk * 1024);
  }
}

__device__ __forceinline__ void compute_tile(const char* lds, int slot, int wr, int wn,
                                             int lr, int lg, f32x4 (&acc)[8][4]) {
  const char* Ab = lds + slot * 65536;
  const char* Bb = Ab + 32768;
  #pragma unroll
  for (int kh = 0; kh < 2; ++kh) {
    bf16x8 afr[8]; bf16x8 bfr[4];
    #pragma unroll
    for (int mi = 0; mi < 8; ++mi) {
      const int row = wr * 128 + mi * 16 + lr;
      afr[mi] = *(const bf16x8*)(Ab + row * 128 + ((kh * 64 + lg * 16) ^ ((row & 7) << 4)));
    }
    #pragma unroll
    for (int ni = 0; ni < 4; ++ni) {
      const int col = wn * 64 + ni * 16 + lr;
      bfr[ni] = *(const bf16x8*)(Bb + col * 128 + ((kh * 64 + lg * 16) ^ ((col & 7) << 4)));
    }
    #pragma unroll
    for (int mi = 0; mi < 8; ++mi)
      #pragma unroll
      for (int ni = 0; ni < 4; ++ni)
        acc[mi][ni] = __builtin_amdgcn_mfma_f32_16x16x32_bf16(afr[mi], bfr[ni], acc[mi][ni], 0, 0, 0);
  }
}

__global__ __launch_bounds__(512, 1) void gemm_lse3(
    const unsigned short* __restrict__ A16, const unsigned short* __restrict__ W16,
    float* __restrict__ part_s) {
  __shared__ char lds[2 * 65536];          // 128 KB: 2 x (A 32KB + B 32KB)
  const char* W16g = (const char*)W16;

  const int tid = threadIdx.x;
  const int lane = tid & 63;
  const int wave = tid >> 6;               // 0..7
  const int lr = lane & 15, lg = lane >> 4;
  const int wr = wave >> 2;                // M half: 0..1
  const int wn = wave & 3;                 // N quarter: 0..3

  // bid -> (mblk, nblk): 4 mblks of one stripe-column land on one XCD (bid&7)
  const int bid = blockIdx.x;              // 256 blocks
  const int x = bid & 7;
  const int q = bid >> 3;                  // 0..31
  const int mblk = q & 3;                  // 0..3
  const int nblk = x * 8 + (q >> 2);       // 0..63
  const int mrow0 = mblk * 256;

  const char* Ab = (const char*)A16 + (size_t)mrow0 * 1024;

  f32x4 acc[8][4];
  #pragma unroll
  for (int mi = 0; mi < 8; ++mi)
    #pragma unroll
    for (int ni = 0; ni < 4; ++ni) acc[mi][ni] = f32x4{0.f, 0.f, 0.f, 0.f};
  float srow[8][4];
  #pragma unroll
  for (int mi = 0; mi < 8; ++mi)
    #pragma unroll
    for (int r = 0; r < 4; ++r) srow[mi][r] = 0.f;

  long s = nblk;                           // stripe index
  long col0 = s * 256;
  stage_tile(Ab, W16g, col0, 0, 0, wave, lane, lds);   // prologue: tile 0 -> slot 0

  while (true) {
    const bool more = (s + NBN) < NST;
    const long ncol0 = (s + NBN) * 256;

    #pragma unroll
    for (int t = 0; t < 8; ++t) {
      __builtin_amdgcn_s_barrier();        // a: compute of slot (t+1)&1 done everywhere
      if (t < 7)      stage_tile(Ab, W16g, col0, t + 1, (t + 1) & 1, wave, lane, lds);
      else if (more)  stage_tile(Ab, W16g, ncol0, 0, 0, wave, lane, lds);
      if (t == 7 && !more) { asm volatile("s_waitcnt vmcnt(0)" ::: "memory"); }
      else                 { asm volatile("s_waitcnt vmcnt(8)" ::: "memory"); }
      __builtin_amdgcn_s_barrier();        // b: tile t (slot t&1) staged & visible
      compute_tile(lds, t & 1, wr, wn, lr, lg, acc);
    }

    // ---- register-only epilogue: fixed max = S, srow += exp2(fma(c,K,-K)) ----
    // (zero-padded W cols contribute exp2(-92.3) ~ 2e-28 -> no masking needed)
    #pragma unroll
    for (int mi = 0; mi < 8; ++mi)
      #pragma unroll
      for (int ni = 0; ni < 4; ++ni)
        #pragma unroll
        for (int r = 0; r < 4; ++r) {
          float c = fminf(1.f, fmaxf(-1.f, acc[mi][ni][r]));   // med3
          srow[mi][r] += exp2f(fmaf(c, S_LOG2E, -S_LOG2E));
          acc[mi][ni][r] = 0.f;
        }

    if (!more) break;
    s += NBN; col0 = ncol0;
  }

  // ---- reduce: lr-lanes (16 cols) in-wave, then 4 wn-waves via LDS ----
  float* ldsrow = (float*)lds;             // 4 wn x 256 rows (pipeline done, LDS free)
  __builtin_amdgcn_s_barrier();
  #pragma unroll
  for (int mi = 0; mi < 8; ++mi)
    #pragma unroll
    for (int r = 0; r < 4; ++r) {
      float v = srow[mi][r];
      v += __shfl_xor(v, 1); v += __shfl_xor(v, 2);
      v += __shfl_xor(v, 4); v += __shfl_xor(v, 8);
      if (lr == 0)
        ldsrow[wn * 256 + wr * 128 + mi * 16 + lg * 4 + r] = v;
    }
  __builtin_amdgcn_s_barrier();
  asm volatile("s_waitcnt lgkmcnt(0)" ::: "memory");
  if (tid < 256) {
    float v = ldsrow[tid] + ldsrow[256 + tid] + ldsrow[512 + tid] + ldsrow[768 + tid];
    part_s[(size_t)nblk * NROWS + mrow0 + tid] = v;
  }
}

// ---------------- kernel 3: precise f32 target logit + merge partials ----------------
__global__ void finalize_kernel(const float* __restrict__ X, const int* __restrict__ labels,
                                const float* __restrict__ Wg, const float* __restrict__ xnorm,
                                const float* __restrict__ part_s, float* __restrict__ rowloss) {
  const int row = blockIdx.x;
  const int lane = threadIdx.x;   // 64
  const int lbl = labels[row];
  const float4* xp = (const float4*)(X + (size_t)row * DIM);
  const float4* wp = (const float4*)(Wg + (size_t)lbl * DIM);
  float dot = 0.f, wss = 0.f;
  #pragma unroll
  for (int i = 0; i < 2; ++i) {
    float4 xv = xp[lane + 64 * i];
    float4 wv = wp[lane + 64 * i];
    dot += xv.x*wv.x + xv.y*wv.y + xv.z*wv.z + xv.w*wv.w;
    wss += wv.x*wv.x + wv.y*wv.y + wv.z*wv.z + wv.w*wv.w;
  }
  float psum = part_s[(size_t)lane * NROWS + row];   // 64 partials per row
  #pragma unroll
  for (int m = 1; m < 64; m <<= 1) {
    dot += __shfl_xor(dot, m); wss += __shfl_xor(wss, m); psum += __shfl_xor(psum, m);
  }
  if (lane == 0) {
    float c = dot / (fmaxf(xnorm[row], 1e-12f) * fmaxf(sqrtf(wss), 1e-12f));
    c = fminf(1.f, fmaxf(-1.f, c));
    const float cm = 0.99500416527802576610f;   // cos(0.1)
    const float sn = 0.09983341664682815230f;   // sin(0.1)
    float unmod = SCALE_S * c;                  // term the GEMM summed at the label column
    float modv  = SCALE_S * (c * cm - sqrtf(fmaxf(0.f, 1.f - c * c)) * sn); // S*cos(theta+m)
    float stot = psum - __expf(unmod - SCALE_S) + __expf(modv - SCALE_S);
    stot = fmaxf(stot, 1e-37f);
    rowloss[row] = (logf(stot) + SCALE_S) - modv;   // logsumexp - target logit
  }
}

// ---------------- kernel 4: mean over rows ----------------
__global__ void reduce_kernel(const float* __restrict__ rowloss, float* __restrict__ out) {
  const int tid = threadIdx.x;   // 256
  float s = 0.f;
  #pragma unroll
  for (int i = 0; i < 4; ++i) s += rowloss[tid + i * 256];
  #pragma unroll
  for (int m = 1; m < 64; m <<= 1) s += __shfl_xor(s, m);
  __shared__ float wsum[4];
  if ((tid & 63) == 0) wsum[tid >> 6] = s;
  __syncthreads();
  if (tid == 0) out[0] = (wsum[0] + wsum[1] + wsum[2] + wsum[3]) * (1.0f / NROWS);
}

extern "C" void kernel_launch(void* const* d_in, const int* in_sizes, int n_in,
                              void* d_out, int out_size, void* d_ws, size_t ws_size,
                              hipStream_t stream) {
  const float* X      = (const float*)d_in[0];
  const int*   labels = (const int*)d_in[1];
  const float* Wg     = (const float*)d_in[2];
  float* out = (float*)d_out;
  char* ws = (char*)d_ws;
  // ws layout (bytes):
  //   A16    @ 0            1,048,576
  //   W16    @ 1,048,576  102,498,304   (100096 x 512 x 2B, rows >= NCLS zeroed)
  //   part_s @ 103,546,880    262,144   (64 x 1024 x 4B)
  //   xnorm  @ 103,809,024      4,096
  //   rowloss@ 103,813,120      4,096
  unsigned short* A16 = (unsigned short*)ws;
  unsigned short* W16 = (unsigned short*)(ws + 1048576);
  float* part_s  = (float*)(ws + 103546880);
  float* xnorm   = (float*)(ws + 103809024);
  float* rowloss = (float*)(ws + 103813120);

  prep_a<<<NROWS, 64, 0, stream>>>(X, A16, xnorm);
  prep_w<<<NCLS_PAD / 4, 256, 0, stream>>>(Wg, W16);
  gemm_lse3<<<256, 512, 0, stream>>>(A16, W16, part_s);
  finalize_kernel<<<NROWS, 64, 0, stream>>>(X, labels, Wg, xnorm, part_s, rowloss);
  reduce_kernel<<<1, 256, 0, stream>>>(rowloss, out);
}

// Round 10
// 275.245 us; speedup vs baseline: 1.1017x; 1.1013x over previous
//
#include <hip/hip_runtime.h>
#include <hip/hip_bf16.h>
#include <stdint.h>

#define DIM 512
#define NROWS 1024
#define NCLS 100000
#define NST 391                         // stripes of 256 cols
#define NCLS_PAD (NST * 256)            // 100096
#define SCALE_S 64.0f
#define NBN 64                          // stripe-columns covered by the grid
#define S_LOG2E 92.332482616893662f     // 64 * log2(e)

typedef __attribute__((ext_vector_type(8))) __bf16 bf16x8;
typedef __attribute__((ext_vector_type(4))) float f32x4;

__device__ __forceinline__ unsigned short f2bf(float x) {
  __hip_bfloat16 h = __float2bfloat16(x);
  union { __hip_bfloat16 h; unsigned short u; } v; v.h = h; return v.u;
}
__device__ __forceinline__ unsigned pack2(float a, float b) {
  return ((unsigned)f2bf(b) << 16) | (unsigned)f2bf(a);
}
__device__ __forceinline__ void async_ld16(const void* g, void* l) {
  __builtin_amdgcn_global_load_lds((const __attribute__((address_space(1))) void*)g,
                                   (__attribute__((address_space(3))) void*)l, 16, 0, 0);
}

// ---------------- kernel 1a: normalize inputs -> bf16 ----------------
__global__ void prep_a(const float* __restrict__ X, unsigned short* __restrict__ A16,
                       float* __restrict__ xnorm) {
  const int row = blockIdx.x;
  const int lane = threadIdx.x;  // 64
  const float4* xp = (const float4*)(X + (size_t)row * DIM);
  float4 v0 = xp[lane];
  float4 v1 = xp[lane + 64];
  float ss = v0.x*v0.x + v0.y*v0.y + v0.z*v0.z + v0.w*v0.w
           + v1.x*v1.x + v1.y*v1.y + v1.z*v1.z + v1.w*v1.w;
  #pragma unroll
  for (int m = 1; m < 64; m <<= 1) ss += __shfl_xor(ss, m);
  const float nrm = sqrtf(ss);
  const float inv = 1.0f / fmaxf(nrm, 1e-12f);
  if (lane == 0) xnorm[row] = nrm;
  unsigned short* ap = A16 + (size_t)row * DIM;
  *(uint2*)(ap + lane * 4)       = make_uint2(pack2(v0.x*inv, v0.y*inv), pack2(v0.z*inv, v0.w*inv));
  *(uint2*)(ap + 256 + lane * 4) = make_uint2(pack2(v1.x*inv, v1.y*inv), pack2(v1.z*inv, v1.w*inv));
}

// ---------------- kernel 1b: normalize weight rows -> bf16 (padded to 100096) ----------------
__global__ void prep_w(const float* __restrict__ Wg, unsigned short* __restrict__ W16) {
  const int row = blockIdx.x * 4 + (threadIdx.x >> 6);
  const int lane = threadIdx.x & 63;
  unsigned short* op = W16 + (size_t)row * DIM;
  if (row >= NCLS) {                       // zero-pad tail rows (cos=0 -> exp(-64)~0)
    *(uint4*)((char*)op + lane * 16) = make_uint4(0, 0, 0, 0);
    return;
  }
  const float4* xp = (const float4*)(Wg + (size_t)row * DIM);
  float4 v0 = xp[lane];
  float4 v1 = xp[lane + 64];
  float ss = v0.x*v0.x + v0.y*v0.y + v0.z*v0.z + v0.w*v0.w
           + v1.x*v1.x + v1.y*v1.y + v1.z*v1.z + v1.w*v1.w;
  #pragma unroll
  for (int m = 1; m < 64; m <<= 1) ss += __shfl_xor(ss, m);
  const float inv = 1.0f / fmaxf(sqrtf(ss), 1e-12f);
  *(uint2*)(op + lane * 4)       = make_uint2(pack2(v0.x*inv, v0.y*inv), pack2(v0.z*inv, v0.w*inv));
  *(uint2*)(op + 256 + lane * 4) = make_uint2(pack2(v1.x*inv, v1.y*inv), pack2(v1.z*inv, v1.w*inv));
}

// ---------------- kernel 2: 256-tile GEMM + fixed-max sumexp partials ----------------
// 512 threads (8 waves = 2M x 4N), block tile BM=256 x stripe 256, BK=64.
// Accumulator acc[8][4] (128 regs) is ANCHORED IN AGPRS ("+a" pins after each
// K-tile): MFMA reads/writes C/D in AGPR natively (zero K-loop copies), arch
// VGPR demand drops to ~110 < the allocator's 128 budget -> no scratch spill.
// (Rounds 8/9: 82.8 MB/dispatch scratch writes, MfmaUtil 16% — spill-bound.)
//
// A+B K-tiles double-buffered in 128KB LDS, staged via global_load_lds (w=16,
// pre-swizzled source, XOR (row&7)<<4). Two raw barriers per K-tile, counted
// s_waitcnt vmcnt(8) (never 0 mid-pipeline), continuous across stripes.

__device__ __forceinline__ void stage_tile(const char* Ab, const char* W16g,
                                           long col0, int kt, int slot,
                                           int wave, int lane, char* lds) {
  char* dstA = lds + slot * 65536;
  char* dstB = dstA + 32768;
  const char* Wb = W16g + (size_t)col0 * 1024;
  #pragma unroll
  for (int it = 0; it < 4; ++it) {
    const int chunk = wave * 4 + it;               // 32 chunks x 1KB each
    const int d = chunk * 1024 + lane * 16;        // linear LDS byte this lane fills
    const int row = d >> 7;                        // tile row/col (128B per row)
    const int b = d & 127;
    const int srel = row * 1024 + kt * 128 + (b ^ ((row & 7) << 4)); // pre-swizzled src
    async_ld16(Ab + srel, dstA + chunk * 1024);    // dest: wave-uniform base
    async_ld16(Wb + srel, dstB + chunk * 1024);
  }
}

__device__ __forceinline__ void compute_tile(const char* lds, int slot, int wr, int wn,
                                             int lr, int lg, f32x4 (&acc)[8][4]) {
  const char* Ab = lds + slot * 65536;
  const char* Bb = Ab + 32768;
  #pragma unroll
  for (int kh = 0; kh < 2; ++kh) {
    bf16x8 afr[8]; bf16x8 bfr[4];
    #pragma unroll
    for (int mi = 0; mi < 8; ++mi) {
      const int row = wr * 128 + mi * 16 + lr;
      afr[mi] = *(const bf16x8*)(Ab + row * 128 + ((kh * 64 + lg * 16) ^ ((row & 7) << 4)));
    }
    #pragma unroll
    for (int ni = 0; ni < 4; ++ni) {
      const int col = wn * 64 + ni * 16 + lr;
      bfr[ni] = *(const bf16x8*)(Bb + col * 128 + ((kh * 64 + lg * 16) ^ ((col & 7) << 4)));
    }
    #pragma unroll
    for (int mi = 0; mi < 8; ++mi)
      #pragma unroll
      for (int ni = 0; ni < 4; ++ni)
        acc[mi][ni] = __builtin_amdgcn_mfma_f32_16x16x32_bf16(afr[mi], bfr[ni], acc[mi][ni], 0, 0, 0);
  }
  // Anchor the accumulator in AGPRs: empty asm, zero instructions when already
  // resident; prevents the allocator from splitting acc's live range into
  // arch VGPRs (where it spilled to scratch in rounds 8/9).
  #pragma unroll
  for (int mi = 0; mi < 8; ++mi)
    #pragma unroll
    for (int ni = 0; ni < 4; ++ni)
      asm volatile("" : "+a"(acc[mi][ni]));
}

__global__ __launch_bounds__(512, 1) void gemm_lse3(
    const unsigned short* __restrict__ A16, const unsigned short* __restrict__ W16,
    float* __restrict__ part_s) {
  __shared__ char lds[2 * 65536];          // 128 KB: 2 x (A 32KB + B 32KB)
  const char* W16g = (const char*)W16;

  const int tid = threadIdx.x;
  const int lane = tid & 63;
  const int wave = tid >> 6;               // 0..7
  const int lr = lane & 15, lg = lane >> 4;
  const int wr = wave >> 2;                // M half: 0..1
  const int wn = wave & 3;                 // N quarter: 0..3

  // bid -> (mblk, nblk): 4 mblks of one stripe-column land on one XCD (bid&7)
  const int bid = blockIdx.x;              // 256 blocks
  const int x = bid & 7;
  const int q = bid >> 3;                  // 0..31
  const int mblk = q & 3;                  // 0..3
  const int nblk = x * 8 + (q >> 2);       // 0..63
  const int mrow0 = mblk * 256;

  const char* Ab = (const char*)A16 + (size_t)mrow0 * 1024;

  f32x4 acc[8][4];
  #pragma unroll
  for (int mi = 0; mi < 8; ++mi)
    #pragma unroll
    for (int ni = 0; ni < 4; ++ni) acc[mi][ni] = f32x4{0.f, 0.f, 0.f, 0.f};
  float srow[8][4];
  #pragma unroll
  for (int mi = 0; mi < 8; ++mi)
    #pragma unroll
    for (int r = 0; r < 4; ++r) srow[mi][r] = 0.f;

  long s = nblk;                           // stripe index
  long col0 = s * 256;
  stage_tile(Ab, W16g, col0, 0, 0, wave, lane, lds);   // prologue: tile 0 -> slot 0

  while (true) {
    const bool more = (s + NBN) < NST;
    const long ncol0 = (s + NBN) * 256;

    #pragma unroll
    for (int t = 0; t < 8; ++t) {
      __builtin_amdgcn_s_barrier();        // a: compute of slot (t+1)&1 done everywhere
      if (t < 7)      stage_tile(Ab, W16g, col0, t + 1, (t + 1) & 1, wave, lane, lds);
      else if (more)  stage_tile(Ab, W16g, ncol0, 0, 0, wave, lane, lds);
      if (t == 7 && !more) { asm volatile("s_waitcnt vmcnt(0)" ::: "memory"); }
      else                 { asm volatile("s_waitcnt vmcnt(8)" ::: "memory"); }
      __builtin_amdgcn_s_barrier();        // b: tile t (slot t&1) staged & visible
      compute_tile(lds, t & 1, wr, wn, lr, lg, acc);
    }

    // ---- register-only epilogue: fixed max = S, srow += exp2(fma(c,K,-K)) ----
    // (zero-padded W cols contribute exp2(-92.3) ~ 2e-28 -> no masking needed)
    #pragma unroll
    for (int mi = 0; mi < 8; ++mi)
      #pragma unroll
      for (int ni = 0; ni < 4; ++ni)
        #pragma unroll
        for (int r = 0; r < 4; ++r) {
          float c = fminf(1.f, fmaxf(-1.f, acc[mi][ni][r]));   // med3
          srow[mi][r] += exp2f(fmaf(c, S_LOG2E, -S_LOG2E));
          acc[mi][ni][r] = 0.f;
        }

    if (!more) break;
    s += NBN; col0 = ncol0;
  }

  // ---- reduce: lr-lanes (16 cols) in-wave, then 4 wn-waves via LDS ----
  float* ldsrow = (float*)lds;             // 4 wn x 256 rows (pipeline done, LDS free)
  __builtin_amdgcn_s_barrier();
  #pragma unroll
  for (int mi = 0; mi < 8; ++mi)
    #pragma unroll
    for (int r = 0; r < 4; ++r) {
      float v = srow[mi][r];
      v += __shfl_xor(v, 1); v += __shfl_xor(v, 2);
      v += __shfl_xor(v, 4); v += __shfl_xor(v, 8);
      if (lr == 0)
        ldsrow[wn * 256 + wr * 128 + mi * 16 + lg * 4 + r] = v;
    }
  __builtin_amdgcn_s_barrier();
  asm volatile("s_waitcnt lgkmcnt(0)" ::: "memory");
  if (tid < 256) {
    float v = ldsrow[tid] + ldsrow[256 + tid] + ldsrow[512 + tid] + ldsrow[768 + tid];
    part_s[(size_t)nblk * NROWS + mrow0 + tid] = v;
  }
}

// ---------------- kernel 3: precise f32 target logit + merge partials ----------------
__global__ void finalize_kernel(const float* __restrict__ X, const int* __restrict__ labels,
                                const float* __restrict__ Wg, const float* __restrict__ xnorm,
                                const float* __restrict__ part_s, float* __restrict__ rowloss) {
  const int row = blockIdx.x;
  const int lane = threadIdx.x;   // 64
  const int lbl = labels[row];
  const float4* xp = (const float4*)(X + (size_t)row * DIM);
  const float4* wp = (const float4*)(Wg + (size_t)lbl * DIM);
  float dot = 0.f, wss = 0.f;
  #pragma unroll
  for (int i = 0; i < 2; ++i) {
    float4 xv = xp[lane + 64 * i];
    float4 wv = wp[lane + 64 * i];
    dot += xv.x*wv.x + xv.y*wv.y + xv.z*wv.z + xv.w*wv.w;
    wss += wv.x*wv.x + wv.y*wv.y + wv.z*wv.z + wv.w*wv.w;
  }
  float psum = part_s[(size_t)lane * NROWS + row];   // 64 partials per row
  #pragma unroll
  for (int m = 1; m < 64; m <<= 1) {
    dot += __shfl_xor(dot, m); wss += __shfl_xor(wss, m); psum += __shfl_xor(psum, m);
  }
  if (lane == 0) {
    float c = dot / (fmaxf(xnorm[row], 1e-12f) * fmaxf(sqrtf(wss), 1e-12f));
    c = fminf(1.f, fmaxf(-1.f, c));
    const float cm = 0.99500416527802576610f;   // cos(0.1)
    const float sn = 0.09983341664682815230f;   // sin(0.1)
    float unmod = SCALE_S * c;                  // term the GEMM summed at the label column
    float modv  = SCALE_S * (c * cm - sqrtf(fmaxf(0.f, 1.f - c * c)) * sn); // S*cos(theta+m)
    float stot = psum - __expf(unmod - SCALE_S) + __expf(modv - SCALE_S);
    stot = fmaxf(stot, 1e-37f);
    rowloss[row] = (logf(stot) + SCALE_S) - modv;   // logsumexp - target logit
  }
}

// ---------------- kernel 4: mean over rows ----------------
__global__ void reduce_kernel(const float* __restrict__ rowloss, float* __restrict__ out) {
  const int tid = threadIdx.x;   // 256
  float s = 0.f;
  #pragma unroll
  for (int i = 0; i < 4; ++i) s += rowloss[tid + i * 256];
  #pragma unroll
  for (int m = 1; m < 64; m <<= 1) s += __shfl_xor(s, m);
  __shared__ float wsum[4];
  if ((tid & 63) == 0) wsum[tid >> 6] = s;
  __syncthreads();
  if (tid == 0) out[0] = (wsum[0] + wsum[1] + wsum[2] + wsum[3]) * (1.0f / NROWS);
}

extern "C" void kernel_launch(void* const* d_in, const int* in_sizes, int n_in,
                              void* d_out, int out_size, void* d_ws, size_t ws_size,
                              hipStream_t stream) {
  const float* X      = (const float*)d_in[0];
  const int*   labels = (const int*)d_in[1];
  const float* Wg     = (const float*)d_in[2];
  float* out = (float*)d_out;
  char* ws = (char*)d_ws;
  // ws layout (bytes):
  //   A16    @ 0            1,048,576
  //   W16    @ 1,048,576  102,498,304   (100096 x 512 x 2B, rows >= NCLS zeroed)
  //   part_s @ 103,546,880    262,144   (64 x 1024 x 4B)
  //   xnorm  @ 103,809,024      4,096
  //   rowloss@ 103,813,120      4,096
  unsigned short* A16 = (unsigned short*)ws;
  unsigned short* W16 = (unsigned short*)(ws + 1048576);
  float* part_s  = (float*)(ws + 103546880);
  float* xnorm   = (float*)(ws + 103809024);
  float* rowloss = (float*)(ws + 103813120);

  prep_a<<<NROWS, 64, 0, stream>>>(X, A16, xnorm);
  prep_w<<<NCLS_PAD / 4, 256, 0, stream>>>(Wg, W16);
  gemm_lse3<<<256, 512, 0, stream>>>(A16, W16, part_s);
  finalize_kernel<<<NROWS, 64, 0, stream>>>(X, labels, Wg, xnorm, part_s, rowloss);
  reduce_kernel<<<1, 256, 0, stream>>>(rowloss, out);
}